// Round 9
// baseline (487.260 us; speedup 1.0000x reference)
//
#include <hip/hip_runtime.h>
#include <hip/hip_bf16.h>
#include <hip/hip_fp16.h>

#define N_NODES 200000
#define N_EDGES 500000
#define F_IN    165
#define HID     256
#define NB      782   // ceil(N_NODES/256) scan blocks

typedef float    floatx4 __attribute__((ext_vector_type(4)));
typedef float    float4u __attribute__((ext_vector_type(4), aligned(4)));
typedef _Float16 half8   __attribute__((ext_vector_type(8)));

// ---------- K0: x (f32, stride 165) -> xh (f16 half8 segs, stride 24 segs) ----------
__global__ void cast_x_kernel(const float* __restrict__ x, half8* __restrict__ xh8) {
    int idx = blockIdx.x * blockDim.x + threadIdx.x;   // < N*24
    int row = idx / 24;
    int p = idx - row * 24;
    int f0 = p * 8;
    const float* px = x + (long)row * F_IN + f0;
    half8 r;
    if (f0 + 8 <= F_IN) {
        float4u lo = *(const float4u*)px;
        float4u hi = *(const float4u*)(px + 4);
#pragma unroll
        for (int q = 0; q < 4; ++q) r[q] = (_Float16)lo[q];
#pragma unroll
        for (int q = 0; q < 4; ++q) r[4 + q] = (_Float16)hi[q];
    } else {
#pragma unroll
        for (int q = 0; q < 8; ++q)
            r[q] = (f0 + q < F_IN) ? (_Float16)px[q] : (_Float16)0.0f;
    }
    xh8[idx] = r;
}

// ---------- K1: edge_index -> f32 output + dst-degree histogram (fused) ----------
__global__ void cast_edges_hist_kernel(const int* __restrict__ ei,
                                       float* __restrict__ oute,
                                       int* __restrict__ degi) {
    int i = blockIdx.x * blockDim.x + threadIdx.x;
    if (i >= 2 * N_EDGES) return;
    int v = ei[i];
    oute[i] = (float)v;
    if (i >= N_EDGES) atomicAdd(&degi[v], 1);
}

// ---------- K2a: per-block degree sums ----------
__global__ __launch_bounds__(256) void block_sum_kernel(const int* __restrict__ degi,
                                                        int* __restrict__ bsum) {
    __shared__ int sh[256];
    int t = threadIdx.x, i = blockIdx.x * 256 + t;
    sh[t] = (i < N_NODES) ? degi[i] : 0;
    __syncthreads();
#pragma unroll
    for (int off = 128; off > 0; off >>= 1) {
        if (t < off) sh[t] += sh[t + off];
        __syncthreads();
    }
    if (t == 0) bsum[blockIdx.x] = sh[0];
}

// ---------- K2b: scan the 782 block sums (1 block) ----------
__global__ __launch_bounds__(1024) void scan_bsum_kernel(const int* __restrict__ bsum,
                                                         int* __restrict__ boff,
                                                         int* __restrict__ row_start) {
    __shared__ int sh[1024];
    int t = threadIdx.x;
    int v = (t < NB) ? bsum[t] : 0;
    sh[t] = v;
    __syncthreads();
    for (int off = 1; off < 1024; off <<= 1) {
        int u = (t >= off) ? sh[t - off] : 0;
        __syncthreads();
        sh[t] += u;
        __syncthreads();
    }
    if (t < NB) boff[t] = sh[t] - v;               // exclusive
    if (t == 1023) row_start[N_NODES] = sh[1023];  // total = E
}

// ---------- K2c: emit row_start / cursor / invdeg ----------
__global__ __launch_bounds__(256) void scan_emit_kernel(const int* __restrict__ degi,
                                                        const int* __restrict__ boff,
                                                        int* __restrict__ row_start,
                                                        int* __restrict__ cursor,
                                                        float* __restrict__ invdeg) {
    __shared__ int sh[256];
    int t = threadIdx.x, i = blockIdx.x * 256 + t;
    int d = (i < N_NODES) ? degi[i] : 0;
    sh[t] = d;
    __syncthreads();
#pragma unroll
    for (int off = 1; off < 256; off <<= 1) {
        int u = (t >= off) ? sh[t - off] : 0;
        __syncthreads();
        sh[t] += u;
        __syncthreads();
    }
    if (i < N_NODES) {
        int row = boff[blockIdx.x] + sh[t] - d;    // exclusive scan value
        row_start[i] = row;
        cursor[i] = row;
        invdeg[i] = 1.0f / fmaxf((float)d, 1.0f);
    }
}

// ---------- K3: bucket edges into CSR ----------
__global__ void scatter_edges_kernel(const int* __restrict__ ei,
                                     int* __restrict__ cursor,
                                     int* __restrict__ csr) {
    int e = blockIdx.x * blockDim.x + threadIdx.x;
    if (e >= N_EDGES) return;
    int s = ei[e];
    int d = ei[N_EDGES + e];
    int pos = atomicAdd(&cursor[d], 1);
    csr[pos] = s;
}

// ---------- K4: pack [w1_r | w1_l] (f16) into MFMA B-fragment order ----------
// chunk c=0..5 -> w1_r (x phase FIRST), c=6..11 -> w1_l (agg phase); kb=(c%6)*32.
__global__ void prep_bfrag_kernel(const float* __restrict__ w1l,
                                  const float* __restrict__ w1r,
                                  _Float16* __restrict__ bfrag) {
    int gid = blockIdx.x * blockDim.x + threadIdx.x;
    if (gid >= 12 * 16 * 64) return;
    int lane = gid & 63;
    int j = (gid >> 6) & 15;
    int c = gid >> 10;
    int quad = lane >> 4, n = lane & 15;
    const float* w = (c < 6) ? w1r : w1l;
    int kb = (c < 6 ? c : c - 6) * 32;
    int col = j * 16 + n;
    half8 r;
#pragma unroll
    for (int q = 0; q < 8; ++q) {
        int k = kb + quad * 8 + q;
        r[q] = (_Float16)((k < F_IN) ? w[k * HID + col] : 0.0f);
    }
    *(half8*)(bfrag + gid * 8) = r;
}

// ---------- K5: fully-fused: in-block CSR gather-agg + MFMA GEMM + relu + layer-2 proj ----------
// x-phase chunks 0..5 DMA'd from xh (pipelined, 4 buffers); agg chunks 6..11 gathered
// in-block from xh via CSR (invdeg applied at gather), ds_write into a 4-deep G ring.
// aggh is NEVER materialized in HBM.
__global__ __launch_bounds__(512, 2) void gemm_fused_kernel(
        const half8* __restrict__ xh8,
        const int* __restrict__ row_start, const int* __restrict__ csr,
        const float* __restrict__ invdeg, const _Float16* __restrict__ bfrag,
        const float* __restrict__ b1,
        const float* __restrict__ w2l, const float* __restrict__ w2r,
        float* __restrict__ tl, float* __restrict__ tr) {
    __shared__ __attribute__((aligned(16))) _Float16 X[4][128 * 32];  // 4 x 8KB x-chunks
    __shared__ __attribute__((aligned(16))) _Float16 G[4][128 * 32];  // 4 x 8KB agg ring
    __shared__ float tlr[128][4];
    const _Float16* xh = (const _Float16*)xh8;
    const int tid = threadIdx.x;
    const int w = tid >> 6, lane = tid & 63;
    const int quad = lane >> 4, l15 = lane & 15;
    const int rowbase = blockIdx.x * 128;
    const int rhalf = (w & 1) * 64;
    const int jbase = (w >> 1) * 4;

    ((float*)tlr)[tid] = 0.0f;   // 512 floats, one per thread

    // staging ids: thread (row_l = tid>>2, lane-slot j = tid&3) fetches swizzled seg
    const int row_l = tid >> 2;
    const int sfetch = (tid & 3) ^ ((row_l >> 1) & 3);
    const int grow = rowbase + row_l;
    const bool growv = grow < N_NODES;
    const int srow = growv ? grow : (N_NODES - 1);   // clamped for DMA safety

    // per-thread gather state (same row & seg-slot for all 6 agg chunks)
    int ge0 = 0, ge1 = 0;
    float ginv = 0.0f;
    if (growv) {
        ge0 = row_start[grow];
        ge1 = row_start[grow + 1];
        ginv = invdeg[grow];
    }
    const int gslot_b = (row_l * 4 + sfetch) * 16;   // byte offset in G[buf]

    floatx4 acc[4][4];
#pragma unroll
    for (int i = 0; i < 4; ++i)
#pragma unroll
        for (int jj = 0; jj < 4; ++jj)
            acc[i][jj] = (floatx4){0.f, 0.f, 0.f, 0.f};

    auto issue = [&](int c, int buf) {   // DMA x-chunk c into X[buf]
        const _Float16* gp = xh + ((long)srow * 24 + c * 4 + sfetch) * 8;
        char* dst = (char*)(&X[buf][0]) + (tid & ~63) * 16;  // wave-uniform base
        __builtin_amdgcn_global_load_lds(
            (const __attribute__((address_space(1))) void*)gp,
            (__attribute__((address_space(3))) void*)dst, 16, 0, 0);
    };

    auto gather = [&](int ac, int buf) { // gather agg chunk ac into G[buf]
        half8 a0 = {0, 0, 0, 0, 0, 0, 0, 0};
        half8 a1 = {0, 0, 0, 0, 0, 0, 0, 0};
        const long segoff = ac * 4 + sfetch;
        int e = ge0;
        for (; e + 2 <= ge1; e += 2) {
            int s0 = csr[e], s1 = csr[e + 1];
            a0 += xh8[(long)s0 * 24 + segoff];
            a1 += xh8[(long)s1 * 24 + segoff];
        }
        if (e < ge1) a0 += xh8[(long)csr[e] * 24 + segoff];
        a0 += a1;
        half8 r;
#pragma unroll
        for (int q = 0; q < 8; ++q) r[q] = (_Float16)((float)a0[q] * ginv);
        *(half8*)((char*)(&G[buf][0]) + gslot_b) = r;
    };

    auto compute = [&](const _Float16* buf, int cc) {  // one 128x256x32 MFMA step
        half8 a[4], b[4];
#pragma unroll
        for (int i = 0; i < 4; ++i) {
            int r = rhalf + i * 16 + l15;
            int slot = r * 4 + (quad ^ ((r >> 1) & 3));
            a[i] = *(const half8*)(buf + slot * 8);
        }
#pragma unroll
        for (int jj = 0; jj < 4; ++jj)
            b[jj] = *(const half8*)(bfrag + (((cc * 16) + jbase + jj) * 64 + lane) * 8);
#pragma unroll
        for (int i = 0; i < 4; ++i)
#pragma unroll
            for (int jj = 0; jj < 4; ++jj)
                acc[i][jj] = __builtin_amdgcn_mfma_f32_16x16x32_f16(a[i], b[jj], acc[i][jj], 0, 0, 0);
    };

    // ---- x-phase (chunks 0..5, w1_r), DMA-pipelined; gathers g0..g3 interleaved ----
    issue(0, 0); issue(1, 1);
    gather(0, 0);
    __syncthreads();                 // drains DMA c0,c1; publishes G0
    issue(2, 2); issue(3, 3);
    compute(&X[0][0], 0); compute(&X[1][0], 1);
    gather(1, 1);
    __syncthreads();                 // drains c2,c3; publishes G1; X0,X1 free
    issue(4, 0); issue(5, 1);
    compute(&X[2][0], 2); compute(&X[3][0], 3);
    gather(2, 2);
    __syncthreads();                 // drains c4,c5; publishes G2
    compute(&X[0][0], 4); compute(&X[1][0], 5);
    gather(3, 3);
    __syncthreads();                 // publishes G3

    // ---- agg phase (chunks 6..11, w1_l) from the G ring ----
#pragma unroll
    for (int ac = 0; ac < 6; ++ac) {
        compute(&G[ac & 3][0], 6 + ac);
        __syncthreads();             // everyone done reading G[ac&3]
        if (ac == 0) gather(4, 0);
        if (ac == 1) gather(5, 1);
    }

    // ---- epilogue: bias+relu, project to 2 classes (l and r), reduce over 16 col-lanes ----
    float bb[4], wl0[4], wl1[4], wr0[4], wr1[4];
#pragma unroll
    for (int jj = 0; jj < 4; ++jj) {
        int col = (w >> 1) * 64 + jj * 16 + l15;
        bb[jj]  = b1[col];
        wl0[jj] = w2l[col * 2];  wl1[jj] = w2l[col * 2 + 1];
        wr0[jj] = w2r[col * 2];  wr1[jj] = w2r[col * 2 + 1];
    }
#pragma unroll
    for (int i = 0; i < 4; ++i) {
#pragma unroll
        for (int t = 0; t < 4; ++t) {
            float s0 = 0.f, s1 = 0.f, s2 = 0.f, s3 = 0.f;
#pragma unroll
            for (int jj = 0; jj < 4; ++jj) {
                float v = fmaxf(acc[i][jj][t] + bb[jj], 0.0f);
                s0 += v * wl0[jj]; s1 += v * wl1[jj];
                s2 += v * wr0[jj]; s3 += v * wr1[jj];
            }
#pragma unroll
            for (int m = 1; m < 16; m <<= 1) {
                s0 += __shfl_xor(s0, m, 64);
                s1 += __shfl_xor(s1, m, 64);
                s2 += __shfl_xor(s2, m, 64);
                s3 += __shfl_xor(s3, m, 64);
            }
            if (l15 == 0) {
                int rl = (w & 1) * 64 + i * 16 + quad * 4 + t;
                atomicAdd(&tlr[rl][0], s0);
                atomicAdd(&tlr[rl][1], s1);
                atomicAdd(&tlr[rl][2], s2);
                atomicAdd(&tlr[rl][3], s3);
            }
        }
    }
    __syncthreads();
    if (tid < 128) {
        int row = rowbase + tid;
        if (row < N_NODES) {
            tl[row * 2 + 0] = tlr[tid][0];
            tl[row * 2 + 1] = tlr[tid][1];
            tr[row * 2 + 0] = tlr[tid][2];
            tr[row * 2 + 1] = tlr[tid][3];
        }
    }
}

// ---------- K6: fused layer-2 gather + finalize (NO atomics) ----------
__global__ void gather_out_kernel(const int* __restrict__ row_start,
                                  const int* __restrict__ csr,
                                  const float* __restrict__ tl,
                                  const float* __restrict__ tr,
                                  const float* __restrict__ invdeg,
                                  const float* __restrict__ b2,
                                  float* __restrict__ out) {
    int i = blockIdx.x * blockDim.x + threadIdx.x;
    if (i >= N_NODES) return;
    int e0 = row_start[i], e1 = row_start[i + 1];
    float a0 = 0.f, a1 = 0.f;
    for (int e = e0; e < e1; ++e) {
        int s = csr[e];
        a0 += tl[s * 2 + 0];
        a1 += tl[s * 2 + 1];
    }
    float inv = invdeg[i];
    out[i * 2 + 0] = a0 * inv + tr[i * 2 + 0] + b2[0];
    out[i * 2 + 1] = a1 * inv + tr[i * 2 + 1] + b2[1];
}

// ---------- workspace layout (bytes) ----------
//   0          degi      800000   (memset 0)
//   800000     row_start 800016   (N+1 ints)
//   1600032    cursor    800000
//   2400032    invdeg    800000
//   3200032    csr       2000000
//   5200032    tl        1600000
//   6800032    tr        1600000
//   8400032    bsum      3200
//   8403232    boff      3200
//   8406432    bfrag     196608
//   8610000    xh        76800000  (f16, 24 half8-segs/row)
extern "C" void kernel_launch(void* const* d_in, const int* in_sizes, int n_in,
                              void* d_out, int out_size, void* d_ws, size_t ws_size,
                              hipStream_t stream) {
    const float* x    = (const float*)d_in[0];
    const int*   ei   = (const int*)d_in[1];
    const float* w1_l = (const float*)d_in[2];
    const float* w1_r = (const float*)d_in[3];
    const float* b1   = (const float*)d_in[4];
    const float* w2_l = (const float*)d_in[5];
    const float* w2_r = (const float*)d_in[6];
    const float* b2   = (const float*)d_in[7];

    char* ws = (char*)d_ws;
    int*   degi      = (int*)(ws);
    int*   row_start = (int*)(ws + 800000);
    int*   cursor    = (int*)(ws + 1600032);
    float* invdeg    = (float*)(ws + 2400032);
    int*   csr       = (int*)(ws + 3200032);
    float* tl        = (float*)(ws + 5200032);
    float* tr        = (float*)(ws + 6800032);
    int*   bsum      = (int*)(ws + 8400032);
    int*   boff      = (int*)(ws + 8403232);
    _Float16* bfrag  = (_Float16*)(ws + 8406432);
    half8* xh8       = (half8*)(ws + 8610000);

    float* out = (float*)d_out;   // f32: logits [0,400000), edges [400000,1400000)

    (void)hipMemsetAsync(degi, 0, 800000, stream);

    cast_edges_hist_kernel<<<(2 * N_EDGES + 255) / 256, 256, 0, stream>>>(
        ei, out + 2 * N_NODES, degi);
    cast_x_kernel<<<(N_NODES * 24) / 256, 256, 0, stream>>>(x, xh8);
    prep_bfrag_kernel<<<48, 256, 0, stream>>>(w1_l, w1_r, bfrag);

    block_sum_kernel<<<NB, 256, 0, stream>>>(degi, bsum);
    scan_bsum_kernel<<<1, 1024, 0, stream>>>(bsum, boff, row_start);
    scan_emit_kernel<<<NB, 256, 0, stream>>>(degi, boff, row_start, cursor, invdeg);
    scatter_edges_kernel<<<(N_EDGES + 255) / 256, 256, 0, stream>>>(ei, cursor, csr);

    gemm_fused_kernel<<<(N_NODES + 127) / 128, 512, 0, stream>>>(
        xh8, row_start, csr, invdeg, bfrag, b1, w2_l, w2_r, tl, tr);

    gather_out_kernel<<<NB, 256, 0, stream>>>(row_start, csr, tl, tr, invdeg, b2, out);
}